// Round 1
// baseline (1570.452 us; speedup 1.0000x reference)
//
#include <hip/hip_runtime.h>
#include <math.h>

// ws layout (floats):
//   accS   [80]     @ 0
//   accQ   [1200]   @ 80
//   accQS  [6000]   @ 1280
//   meanS  [10400]  @ 7280
//   invS   [10400]  @ 17680
//   meanQ  [30000]  @ 28080
//   invQ   [30000]  @ 58080   (end 88080 floats = 352 KB)

#define ALPHA_EXP_SCALE (-0.125f * 1.44269504088896340736f)

__global__ void zero_kernel(float* __restrict__ p, int n) {
  int i = blockIdx.x * blockDim.x + threadIdx.x;
  if (i < n) p[i] = 0.f;
}

// one wave per vector: mean + inv-norm of centered vector
__global__ void stats_kernel(const float* __restrict__ x,
                             float* __restrict__ mean,
                             float* __restrict__ inv,
                             int nvec) {
  int wid = ((int)blockIdx.x * (int)blockDim.x + (int)threadIdx.x) >> 6;
  int lane = threadIdx.x & 63;
  if (wid >= nvec) return;
  const float* base = x + (size_t)wid * 640;
  float s = 0.f, ss = 0.f;
#pragma unroll
  for (int k = 0; k < 10; ++k) {
    float v = base[lane + (k << 6)];
    s += v;
    ss += v * v;
  }
#pragma unroll
  for (int m = 1; m < 64; m <<= 1) {
    s += __shfl_xor(s, m, 64);
    ss += __shfl_xor(ss, m, 64);
  }
  if (lane == 0) {
    float varsum = fmaxf(ss - s * s * (1.f / 640.f), 0.f);
    mean[wid] = s * (1.f / 640.f);
    inv[wid] = 1.f / sqrtf(varsum + 1e-12f);
  }
}

// Tiled gram + fused multi-gauss + cell reduction.
// Grid: (tilesI, tilesJ, groups). 256 threads as 16x16, MT x MT micro-tile.
// Cells: entry (i,j) -> acc[g*accPerGroup + (j/DIVJ)*CELLSI + (i/DIVI)].
template <int BT, int MT, int NI, int NJ, int DIVI, int DIVJ, int CELLSI, int SELFSKIP>
__global__ __launch_bounds__(256) void gram_kernel(
    const float* __restrict__ X, const float* __restrict__ Y,
    const float* __restrict__ mX, const float* __restrict__ iX,
    const float* __restrict__ mY, const float* __restrict__ iY,
    int nx, int ny, int accPerGroup, float* __restrict__ acc) {
  constexpr int CH = 64;
  constexpr int CHP = CH + 4;  // +4 floats: float4-aligned, banks spread
  __shared__ float xs[BT][CHP];
  __shared__ float ys[BT][CHP];
  __shared__ float mxs[BT], ixs[BT], mys[BT], iys[BT];

  const int g = blockIdx.z;
  const int i0 = blockIdx.x * BT;
  const int j0 = blockIdx.y * BT;
  const int tid = threadIdx.x;
  const int tx = tid & 15;
  const int ty = tid >> 4;

  const float* Xg = X + (size_t)g * nx * 640;
  const float* Yg = Y + (size_t)g * ny * 640;
  const float* mXg = mX + (size_t)g * nx;
  const float* iXg = iX + (size_t)g * nx;
  const float* mYg = mY + (size_t)g * ny;
  const float* iYg = iY + (size_t)g * ny;

  if (tid < BT) {
    int r = i0 + tid;
    bool v = r < nx;
    mxs[tid] = v ? mXg[r] : 0.f;
    ixs[tid] = v ? iXg[r] : 0.f;
  } else if (tid < 2 * BT) {
    int t2 = tid - BT;
    int r = j0 + t2;
    bool v = r < ny;
    mys[t2] = v ? mYg[r] : 0.f;
    iys[t2] = v ? iYg[r] : 0.f;
  }
  __syncthreads();

  float accv[MT][MT];
#pragma unroll
  for (int k = 0; k < MT; ++k)
#pragma unroll
    for (int l = 0; l < MT; ++l) accv[k][l] = 0.f;

  for (int c0 = 0; c0 < 640; c0 += CH) {
    // stage tiles, normalization applied on the fly
#pragma unroll
    for (int m = 0; m < (BT * CH) / 256; ++m) {
      int e = tid + m * 256;
      int r = e >> 6;
      int cc = e & 63;
      int ri = i0 + r;
      float v = 0.f;
      if (ri < nx) v = (Xg[(size_t)ri * 640 + c0 + cc] - mxs[r]) * ixs[r];
      xs[r][cc] = v;
      int rj = j0 + r;
      float v2 = 0.f;
      if (rj < ny) v2 = (Yg[(size_t)rj * 640 + c0 + cc] - mys[r]) * iys[r];
      ys[r][cc] = v2;
    }
    __syncthreads();
    for (int c4 = 0; c4 < CH / 4; ++c4) {
      float4 a4[MT], b4[MT];
#pragma unroll
      for (int k = 0; k < MT; ++k)
        a4[k] = *reinterpret_cast<const float4*>(&xs[ty + 16 * k][c4 * 4]);
#pragma unroll
      for (int l = 0; l < MT; ++l)
        b4[l] = *reinterpret_cast<const float4*>(&ys[tx + 16 * l][c4 * 4]);
#pragma unroll
      for (int k = 0; k < MT; ++k)
#pragma unroll
        for (int l = 0; l < MT; ++l) {
          accv[k][l] = fmaf(a4[k].x, b4[l].x, accv[k][l]);
          accv[k][l] = fmaf(a4[k].y, b4[l].y, accv[k][l]);
          accv[k][l] = fmaf(a4[k].z, b4[l].z, accv[k][l]);
          accv[k][l] = fmaf(a4[k].w, b4[l].w, accv[k][l]);
        }
    }
    __syncthreads();
  }

  // epilogue: multi-gauss + per-cell predicated accumulation
  int rg_[MT], cg_[MT], ci_[MT], cj_[MT];
#pragma unroll
  for (int k = 0; k < MT; ++k) {
    rg_[k] = i0 + ty + 16 * k;
    ci_[k] = rg_[k] / DIVI;
  }
#pragma unroll
  for (int l = 0; l < MT; ++l) {
    cg_[l] = j0 + tx + 16 * l;
    cj_[l] = cg_[l] / DIVJ;
  }
  const int ci0 = i0 / DIVI;
  const int cj0 = j0 / DIVJ;

  float cell[NI][NJ];
#pragma unroll
  for (int a = 0; a < NI; ++a)
#pragma unroll
    for (int b = 0; b < NJ; ++b) cell[a][b] = 0.f;

#pragma unroll
  for (int k = 0; k < MT; ++k) {
#pragma unroll
    for (int l = 0; l < MT; ++l) {
      // unit-norm rows: d2 = |x|^2+|y|^2-2g = 2-2g (clamped)
      float d2 = fmaxf(2.f - 2.f * accv[k][l], 0.f);
      // sum_a exp(-a*d2), a = 0.125*2^k: e^1+e^2+e^4+e^8+e^16
      float e1 = exp2f(d2 * ALPHA_EXP_SCALE);
      float e2 = e1 * e1;
      float e4 = e2 * e2;
      float e8 = e4 * e4;
      float e16 = e8 * e8;
      float kv = e1 + e2 + e4 + e8 + e16;
      bool valid = (rg_[k] < nx) && (cg_[l] < ny);
      if (SELFSKIP) valid = valid && (rg_[k] != cg_[l]);
      kv = valid ? kv : 0.f;
#pragma unroll
      for (int a = 0; a < NI; ++a)
#pragma unroll
        for (int b = 0; b < NJ; ++b) {
          bool inc = (ci_[k] == ci0 + a) && (cj_[l] == cj0 + b);
          cell[a][b] += inc ? kv : 0.f;
        }
    }
  }

#pragma unroll
  for (int a = 0; a < NI; ++a)
#pragma unroll
    for (int b = 0; b < NJ; ++b) {
      float v = cell[a][b];
#pragma unroll
      for (int m = 1; m < 64; m <<= 1) v += __shfl_xor(v, m, 64);
      if ((tid & 63) == 0) {
        long cI = ci0 + a;
        long cJ = cj0 + b;
        if (cI * (long)DIVI < (long)nx && cJ * (long)DIVJ < (long)ny)
          atomicAdd(&acc[(size_t)g * accPerGroup + (int)cJ * CELLSI + (int)cI], v);
      }
    }
}

__global__ void finalize_kernel(const float* __restrict__ accS,
                                const float* __restrict__ accQ,
                                const float* __restrict__ accQS,
                                float* __restrict__ out) {
  int t = blockIdx.x * blockDim.x + threadIdx.x;
  if (t >= 6000) return;
  int w = t % 5;
  int bq = t / 5;  // b*75+q
  int b = t / 375;
  out[t] = accS[b * 5 + w] * (1.f / (130.f * 129.f)) +
           accQ[bq] * (1.f / (25.f * 24.f)) -
           accQS[t] * (2.f / (130.f * 25.f));
}

extern "C" void kernel_launch(void* const* d_in, const int* in_sizes, int n_in,
                              void* d_out, int out_size, void* d_ws, size_t ws_size,
                              hipStream_t stream) {
  const float* S = (const float*)d_in[0];  // [16,5,130,640]
  const float* Q = (const float*)d_in[1];  // [16,75,25,640]
  float* ws = (float*)d_ws;
  float* accS = ws + 0;
  float* accQ = ws + 80;
  float* accQS = ws + 1280;
  float* meanS = ws + 7280;
  float* invS = ws + 17680;
  float* meanQ = ws + 28080;
  float* invQ = ws + 58080;
  float* out = (float*)d_out;

  zero_kernel<<<(7280 + 255) / 256, 256, 0, stream>>>(ws, 7280);
  stats_kernel<<<(10400 + 3) / 4, 256, 0, stream>>>(S, meanS, invS, 10400);
  stats_kernel<<<(30000 + 3) / 4, 256, 0, stream>>>(Q, meanQ, invQ, 30000);

  // cross: per b, S_b[650,640] x T_b[1875,640]^T; cells (w=i/130, q=j/25)
  {
    dim3 grid((650 + 63) / 64, (1875 + 63) / 64, 16);
    gram_kernel<64, 4, 2, 4, 130, 25, 5, 0><<<grid, 256, 0, stream>>>(
        S, Q, meanS, invS, meanQ, invQ, 650, 1875, 375, accQS);
  }
  // self-support: per (b,w), S_bw[130,640] self-gram, skip diagonal
  {
    dim3 grid((130 + 31) / 32, (130 + 31) / 32, 80);
    gram_kernel<32, 2, 1, 1, (1 << 30), (1 << 30), 1, 1><<<grid, 256, 0, stream>>>(
        S, S, meanS, invS, meanS, invS, 130, 130, 1, accS);
  }
  // self-query: per (b,q), T_bq[25,640] self-gram, skip diagonal
  {
    dim3 grid(1, 1, 1200);
    gram_kernel<32, 2, 1, 1, (1 << 30), (1 << 30), 1, 1><<<grid, 256, 0, stream>>>(
        Q, Q, meanQ, invQ, meanQ, invQ, 25, 25, 1, accQ);
  }
  finalize_kernel<<<(6000 + 255) / 256, 256, 0, stream>>>(accS, accQ, accQS, out);
}

// Round 2
// 327.629 us; speedup vs baseline: 4.7934x; 4.7934x over previous
//
#include <hip/hip_runtime.h>
#include <math.h>

#define ALPHA_EXP_SCALE (-0.125f * 1.44269504088896340736f)

typedef __attribute__((ext_vector_type(8))) short bf16x8_t;
typedef __attribute__((ext_vector_type(4))) float f32x4_t;

#define GLOAD_LDS16(g, l)                                      \
  __builtin_amdgcn_global_load_lds(                            \
      (const __attribute__((address_space(1))) void*)(g),      \
      (__attribute__((address_space(3))) void*)(l), 16, 0, 0)

__device__ __forceinline__ unsigned short f2bf(float f) {
  unsigned int u = __float_as_uint(f);
  unsigned int r = (u + 0x7fffu + ((u >> 16) & 1u)) >> 16;
  return (unsigned short)r;
}
__device__ __forceinline__ float bf2f(unsigned short h) {
  return __uint_as_float(((unsigned int)h) << 16);
}

__global__ void zero_kernel(float* __restrict__ p, int n) {
  int i = blockIdx.x * blockDim.x + threadIdx.x;
  if (i < n) p[i] = 0.f;
}

// ---------------- MFMA path ----------------

// one wave per vector: center + l2norm + hi/lo bf16 split, K'=1280 layout
__global__ void prep_kernel(const float* __restrict__ x,
                            unsigned short* __restrict__ out, int nvec) {
  int wid = ((int)blockIdx.x * (int)blockDim.x + (int)threadIdx.x) >> 6;
  int lane = threadIdx.x & 63;
  if (wid >= nvec) return;
  const float* base = x + (size_t)wid * 640;
  float v[10];
  float s = 0.f, ss = 0.f;
#pragma unroll
  for (int k = 0; k < 10; ++k) {
    v[k] = base[lane + (k << 6)];
    s += v[k];
    ss += v[k] * v[k];
  }
#pragma unroll
  for (int m = 1; m < 64; m <<= 1) {
    s += __shfl_xor(s, m, 64);
    ss += __shfl_xor(ss, m, 64);
  }
  float mean = s * (1.f / 640.f);
  float varsum = fmaxf(ss - s * s * (1.f / 640.f), 0.f);
  float inv = 1.f / sqrtf(varsum + 1e-12f);
  unsigned short* o = out + (size_t)wid * 1280;
#pragma unroll
  for (int k = 0; k < 10; ++k) {
    float t = (v[k] - mean) * inv;
    unsigned short hi = f2bf(t);
    float lo = t - bf2f(hi);
    o[lane + (k << 6)] = hi;
    o[640 + lane + (k << 6)] = f2bf(lo);
  }
}

// 128x128 tile, 4 waves (2x2) of 64x64, K'=1280 bf16 (hi|lo), 2-phase
// global_load_lds staging with pre-swizzled source (XOR (r&7) on 16B slots).
// Epilogue: multi-gauss + predicated cell accumulation + wave reduce + atomic.
// SELF=1: only entries with r/DIV == c/DIV and r != c count; cell = r/DIV.
template <int NI, int NJ, int DIVI, int DIVJ, int CELLSI, int SELF>
__global__ __launch_bounds__(256) void mgram_kernel(
    const unsigned short* __restrict__ X, const unsigned short* __restrict__ Y,
    long gsx, long gsy, int nx, int ny, int app, float* __restrict__ acc) {
  __shared__ __align__(16) unsigned short sA[2][128 * 64];
  __shared__ __align__(16) unsigned short sB[2][128 * 64];
  const int g = blockIdx.z;
  const int i0 = blockIdx.x * 128;
  const int j0 = blockIdx.y * 128;
  const int tid = threadIdx.x;
  const int w = tid >> 6;
  const int l = tid & 63;
  const unsigned short* Xg = X + (size_t)g * gsx;
  const unsigned short* Yg = Y + (size_t)g * gsy;

  f32x4_t av[4][4];
#pragma unroll
  for (int i = 0; i < 4; ++i)
#pragma unroll
    for (int j = 0; j < 4; ++j)
#pragma unroll
      for (int r = 0; r < 4; ++r) av[i][j][r] = 0.f;

  const int wr = w >> 1, wc = w & 1;
  const int R0 = wr * 64, C0 = wc * 64;
  const int lr = l & 15, lk8 = (l >> 4) * 8;

  // staging geometry (per thread, 4 slices each for A and B)
  int st_r[4], st_c16[4];
#pragma unroll
  for (int i = 0; i < 4; ++i) {
    int slice = w * 4 + i;
    int s = slice * 64 + l;
    st_r[i] = s >> 3;
    st_c16[i] = (s & 7) ^ (st_r[i] & 7);
  }

#define STAGE(bb, chunk)                                                      \
  {                                                                           \
    int kbase = (chunk) * 64;                                                 \
    _Pragma("unroll") for (int i = 0; i < 4; ++i) {                           \
      int slice = w * 4 + i;                                                  \
      int r = st_r[i], c16 = st_c16[i];                                       \
      int vi = i0 + r;                                                        \
      vi = vi < nx ? vi : nx - 1;                                             \
      GLOAD_LDS16(Xg + (size_t)vi * 1280 + kbase + c16 * 8,                   \
                  &sA[bb][slice * 512]);                                      \
      int vj = j0 + r;                                                        \
      vj = vj < ny ? vj : ny - 1;                                             \
      GLOAD_LDS16(Yg + (size_t)vj * 1280 + kbase + c16 * 8,                   \
                  &sB[bb][slice * 512]);                                      \
    }                                                                         \
  }

#define COMPUTE(bb)                                                           \
  {                                                                           \
    _Pragma("unroll") for (int ks = 0; ks < 2; ++ks) {                        \
      bf16x8_t af[4], bfr[4];                                                 \
      int kk = ks * 32 + lk8;                                                 \
      _Pragma("unroll") for (int t = 0; t < 4; ++t) {                         \
        int rr_ = R0 + t * 16 + lr;                                           \
        af[t] = *(const bf16x8_t*)&sA[bb][rr_ * 64 + (kk ^ ((rr_ & 7) << 3))];\
        int cc_ = C0 + t * 16 + lr;                                           \
        bfr[t] =                                                              \
            *(const bf16x8_t*)&sB[bb][cc_ * 64 + (kk ^ ((cc_ & 7) << 3))];    \
      }                                                                       \
      _Pragma("unroll") for (int i = 0; i < 4; ++i)                           \
          _Pragma("unroll") for (int j = 0; j < 4; ++j) av[i][j] =            \
          __builtin_amdgcn_mfma_f32_16x16x32_bf16(af[i], bfr[j], av[i][j], 0, \
                                                  0, 0);                      \
    }                                                                         \
  }

  STAGE(0, 0);
  __syncthreads();
  for (int c = 0; c < 20; ++c) {
    if (c < 19) STAGE((c + 1) & 1, c + 1);
    COMPUTE(c & 1);
    __syncthreads();
  }
#undef STAGE
#undef COMPUTE

  // epilogue
  float cell[NI][NJ];
#pragma unroll
  for (int a = 0; a < NI; ++a)
#pragma unroll
    for (int b = 0; b < NJ; ++b) cell[a][b] = 0.f;

  const int cbi = (i0 + R0) / DIVI;
  const int cbj = (j0 + C0) / DIVJ;

#pragma unroll
  for (int i = 0; i < 4; ++i) {
#pragma unroll
    for (int rr = 0; rr < 4; ++rr) {
      int gr = i0 + R0 + i * 16 + (l >> 4) * 4 + rr;
      int gri = gr / DIVI;
#pragma unroll
      for (int j = 0; j < 4; ++j) {
        int gc = j0 + C0 + j * 16 + lr;
        int gcd = gc / DIVJ;
        float gv = av[i][j][rr];
        float d2 = fmaxf(2.f - 2.f * gv, 0.f);
        float e1 = exp2f(d2 * ALPHA_EXP_SCALE);
        float e2 = e1 * e1, e4 = e2 * e2, e8 = e4 * e4, e16 = e8 * e8;
        float kv = e1 + e2 + e4 + e8 + e16;
        if (SELF) {
          bool neq = gr != gc;
#pragma unroll
          for (int a = 0; a < NI; ++a) {
            bool inc = (gri == cbi + a) && (gcd == cbi + a) && neq;
            cell[a][0] += inc ? kv : 0.f;
          }
        } else {
#pragma unroll
          for (int a = 0; a < NI; ++a)
#pragma unroll
            for (int b = 0; b < NJ; ++b) {
              bool inc = (gri == cbi + a) && (gcd == cbj + b);
              cell[a][b] += inc ? kv : 0.f;
            }
        }
      }
    }
  }

#pragma unroll
  for (int a = 0; a < NI; ++a)
#pragma unroll
    for (int b = 0; b < NJ; ++b) {
      float v2 = cell[a][b];
#pragma unroll
      for (int m = 1; m < 64; m <<= 1) v2 += __shfl_xor(v2, m, 64);
      if (l == 0) {
        int ci = cbi + a;
        if (SELF) {
          if ((long)ci * DIVI < (long)nx)
            atomicAdd(&acc[(size_t)g * app + ci], v2);
        } else {
          int cj = cbj + b;
          if ((long)ci * DIVI < (long)nx && (long)cj * DIVJ < (long)ny)
            atomicAdd(&acc[(size_t)g * app + cj * CELLSI + ci], v2);
        }
      }
    }
}

__global__ void finalize_kernel(const float* __restrict__ accS,
                                const float* __restrict__ accQ,
                                const float* __restrict__ accQS,
                                float* __restrict__ out) {
  int t = blockIdx.x * blockDim.x + threadIdx.x;
  if (t >= 6000) return;
  int w = t % 5;
  int bq = t / 5;  // b*75+q
  int b = t / 375;
  out[t] = accS[b * 5 + w] * (1.f / (130.f * 129.f)) +
           accQ[bq] * (1.f / (25.f * 24.f)) - accQS[t] * (2.f / (130.f * 25.f));
}

// ---------------- fallback fp32 path (round-1, passing) ----------------

__global__ void stats_kernel(const float* __restrict__ x,
                             float* __restrict__ mean, float* __restrict__ inv,
                             int nvec) {
  int wid = ((int)blockIdx.x * (int)blockDim.x + (int)threadIdx.x) >> 6;
  int lane = threadIdx.x & 63;
  if (wid >= nvec) return;
  const float* base = x + (size_t)wid * 640;
  float s = 0.f, ss = 0.f;
#pragma unroll
  for (int k = 0; k < 10; ++k) {
    float v = base[lane + (k << 6)];
    s += v;
    ss += v * v;
  }
#pragma unroll
  for (int m = 1; m < 64; m <<= 1) {
    s += __shfl_xor(s, m, 64);
    ss += __shfl_xor(ss, m, 64);
  }
  if (lane == 0) {
    float varsum = fmaxf(ss - s * s * (1.f / 640.f), 0.f);
    mean[wid] = s * (1.f / 640.f);
    inv[wid] = 1.f / sqrtf(varsum + 1e-12f);
  }
}

template <int BT, int MT, int NI, int NJ, int DIVI, int DIVJ, int CELLSI,
          int SELFSKIP>
__global__ __launch_bounds__(256) void gram_kernel(
    const float* __restrict__ X, const float* __restrict__ Y,
    const float* __restrict__ mX, const float* __restrict__ iX,
    const float* __restrict__ mY, const float* __restrict__ iY, int nx, int ny,
    int accPerGroup, float* __restrict__ acc) {
  constexpr int CH = 64;
  constexpr int CHP = CH + 4;
  __shared__ float xs[BT][CHP];
  __shared__ float ys[BT][CHP];
  __shared__ float mxs[BT], ixs[BT], mys[BT], iys[BT];

  const int g = blockIdx.z;
  const int i0 = blockIdx.x * BT;
  const int j0 = blockIdx.y * BT;
  const int tid = threadIdx.x;
  const int tx = tid & 15;
  const int ty = tid >> 4;

  const float* Xg = X + (size_t)g * nx * 640;
  const float* Yg = Y + (size_t)g * ny * 640;
  const float* mXg = mX + (size_t)g * nx;
  const float* iXg = iX + (size_t)g * nx;
  const float* mYg = mY + (size_t)g * ny;
  const float* iYg = iY + (size_t)g * ny;

  if (tid < BT) {
    int r = i0 + tid;
    bool v = r < nx;
    mxs[tid] = v ? mXg[r] : 0.f;
    ixs[tid] = v ? iXg[r] : 0.f;
  } else if (tid < 2 * BT) {
    int t2 = tid - BT;
    int r = j0 + t2;
    bool v = r < ny;
    mys[t2] = v ? mYg[r] : 0.f;
    iys[t2] = v ? iYg[r] : 0.f;
  }
  __syncthreads();

  float accv[MT][MT];
#pragma unroll
  for (int k = 0; k < MT; ++k)
#pragma unroll
    for (int l = 0; l < MT; ++l) accv[k][l] = 0.f;

  for (int c0 = 0; c0 < 640; c0 += CH) {
#pragma unroll
    for (int m = 0; m < (BT * CH) / 256; ++m) {
      int e = tid + m * 256;
      int r = e >> 6;
      int cc = e & 63;
      int ri = i0 + r;
      float v = 0.f;
      if (ri < nx) v = (Xg[(size_t)ri * 640 + c0 + cc] - mxs[r]) * ixs[r];
      xs[r][cc] = v;
      int rj = j0 + r;
      float v2 = 0.f;
      if (rj < ny) v2 = (Yg[(size_t)rj * 640 + c0 + cc] - mys[r]) * iys[r];
      ys[r][cc] = v2;
    }
    __syncthreads();
    for (int c4 = 0; c4 < CH / 4; ++c4) {
      float4 a4[MT], b4[MT];
#pragma unroll
      for (int k = 0; k < MT; ++k)
        a4[k] = *reinterpret_cast<const float4*>(&xs[ty + 16 * k][c4 * 4]);
#pragma unroll
      for (int l = 0; l < MT; ++l)
        b4[l] = *reinterpret_cast<const float4*>(&ys[tx + 16 * l][c4 * 4]);
#pragma unroll
      for (int k = 0; k < MT; ++k)
#pragma unroll
        for (int l = 0; l < MT; ++l) {
          accv[k][l] = fmaf(a4[k].x, b4[l].x, accv[k][l]);
          accv[k][l] = fmaf(a4[k].y, b4[l].y, accv[k][l]);
          accv[k][l] = fmaf(a4[k].z, b4[l].z, accv[k][l]);
          accv[k][l] = fmaf(a4[k].w, b4[l].w, accv[k][l]);
        }
    }
    __syncthreads();
  }

  int rg_[MT], cg_[MT], ci_[MT], cj_[MT];
#pragma unroll
  for (int k = 0; k < MT; ++k) {
    rg_[k] = i0 + ty + 16 * k;
    ci_[k] = rg_[k] / DIVI;
  }
#pragma unroll
  for (int l = 0; l < MT; ++l) {
    cg_[l] = j0 + tx + 16 * l;
    cj_[l] = cg_[l] / DIVJ;
  }
  const int ci0 = i0 / DIVI;
  const int cj0 = j0 / DIVJ;

  float cell[NI][NJ];
#pragma unroll
  for (int a = 0; a < NI; ++a)
#pragma unroll
    for (int b = 0; b < NJ; ++b) cell[a][b] = 0.f;

#pragma unroll
  for (int k = 0; k < MT; ++k) {
#pragma unroll
    for (int l = 0; l < MT; ++l) {
      float d2 = fmaxf(2.f - 2.f * accv[k][l], 0.f);
      float e1 = exp2f(d2 * ALPHA_EXP_SCALE);
      float e2 = e1 * e1;
      float e4 = e2 * e2;
      float e8 = e4 * e4;
      float e16 = e8 * e8;
      float kv = e1 + e2 + e4 + e8 + e16;
      bool valid = (rg_[k] < nx) && (cg_[l] < ny);
      if (SELFSKIP) valid = valid && (rg_[k] != cg_[l]);
      kv = valid ? kv : 0.f;
#pragma unroll
      for (int a = 0; a < NI; ++a)
#pragma unroll
        for (int b = 0; b < NJ; ++b) {
          bool inc = (ci_[k] == ci0 + a) && (cj_[l] == cj0 + b);
          cell[a][b] += inc ? kv : 0.f;
        }
    }
  }

#pragma unroll
  for (int a = 0; a < NI; ++a)
#pragma unroll
    for (int b = 0; b < NJ; ++b) {
      float v = cell[a][b];
#pragma unroll
      for (int m = 1; m < 64; m <<= 1) v += __shfl_xor(v, m, 64);
      if ((tid & 63) == 0) {
        long cI = ci0 + a;
        long cJ = cj0 + b;
        if (cI * (long)DIVI < (long)nx && cJ * (long)DIVJ < (long)ny)
          atomicAdd(&acc[(size_t)g * accPerGroup + (int)cJ * CELLSI + (int)cI],
                    v);
      }
    }
}

// ---------------- launch ----------------

extern "C" void kernel_launch(void* const* d_in, const int* in_sizes, int n_in,
                              void* d_out, int out_size, void* d_ws,
                              size_t ws_size, hipStream_t stream) {
  const float* S = (const float*)d_in[0];  // [16,5,130,640]
  const float* Q = (const float*)d_in[1];  // [16,75,25,640]
  float* ws = (float*)d_ws;
  float* accS = ws + 0;
  float* accQ = ws + 80;
  float* accQS = ws + 1280;
  float* out = (float*)d_out;

  const size_t NEED = 7280ull * 4 + (10400ull + 30000ull) * 1280 * 2;

  if (ws_size >= NEED) {
    unsigned short* SHL = (unsigned short*)(ws + 7280);
    unsigned short* QHL = SHL + (size_t)10400 * 1280;

    zero_kernel<<<(7280 + 255) / 256, 256, 0, stream>>>(ws, 7280);
    prep_kernel<<<2600, 256, 0, stream>>>(S, SHL, 10400);
    prep_kernel<<<7500, 256, 0, stream>>>(Q, QHL, 30000);

    // cross: per b, [650,1280] x [1875,1280]^T; cells (w=r/130, q=c/25)
    {
      dim3 grid(6, 15, 16);
      mgram_kernel<2, 4, 130, 25, 5, 0><<<grid, 256, 0, stream>>>(
          SHL, QHL, 650L * 1280, 1875L * 1280, 650, 1875, 375, accQS);
    }
    // self-support: per (b,w): 130x130, diag skipped, 1 cell
    {
      dim3 grid(2, 2, 80);
      mgram_kernel<2, 1, 130, 130, 1, 1><<<grid, 256, 0, stream>>>(
          SHL, SHL, 130L * 1280, 130L * 1280, 130, 130, 1, accS);
    }
    // self-query: per (b, 5-q-group tile): 125x125, block-diag by 25
    {
      dim3 grid(1, 1, 240);
      mgram_kernel<4, 1, 25, 25, 1, 1><<<grid, 256, 0, stream>>>(
          QHL, QHL, 125L * 1280, 125L * 1280, 125, 125, 5, accQ);
    }
    finalize_kernel<<<(6000 + 255) / 256, 256, 0, stream>>>(accS, accQ, accQS,
                                                            out);
  } else {
    // fallback: round-1 fp32 path
    float* meanS = ws + 7280;
    float* invS = ws + 17680;
    float* meanQ = ws + 28080;
    float* invQ = ws + 58080;

    zero_kernel<<<(7280 + 255) / 256, 256, 0, stream>>>(ws, 7280);
    stats_kernel<<<(10400 + 3) / 4, 256, 0, stream>>>(S, meanS, invS, 10400);
    stats_kernel<<<(30000 + 3) / 4, 256, 0, stream>>>(Q, meanQ, invQ, 30000);
    {
      dim3 grid((650 + 63) / 64, (1875 + 63) / 64, 16);
      gram_kernel<64, 4, 2, 4, 130, 25, 5, 0><<<grid, 256, 0, stream>>>(
          S, Q, meanS, invS, meanQ, invQ, 650, 1875, 375, accQS);
    }
    {
      dim3 grid((130 + 31) / 32, (130 + 31) / 32, 80);
      gram_kernel<32, 2, 1, 1, (1 << 30), (1 << 30), 1, 1>
          <<<grid, 256, 0, stream>>>(S, S, meanS, invS, meanS, invS, 130, 130,
                                     1, accS);
    }
    {
      dim3 grid(1, 1, 1200);
      gram_kernel<32, 2, 1, 1, (1 << 30), (1 << 30), 1, 1>
          <<<grid, 256, 0, stream>>>(Q, Q, meanQ, invQ, meanQ, invQ, 25, 25, 1,
                                     accQ);
    }
    finalize_kernel<<<(6000 + 255) / 256, 256, 0, stream>>>(accS, accQ, accQS,
                                                            out);
  }
}

// Round 3
// 282.148 us; speedup vs baseline: 5.5661x; 1.1612x over previous
//
#include <hip/hip_runtime.h>
#include <math.h>

// ws layout (floats):
//   accS [80] @0, accQ [1200] @80, accQS [6000] @1280, SHL(u16) @7280,
//   QHL(u16) after SHL. SHL: 10400 rows x 1280 u16; QHL: 30000 x 1280.

#define EXP_C (-0.25f * 1.44269504088896340736f)  // 2*(-0.125)*log2(e)

typedef __attribute__((ext_vector_type(8))) short bf16x8_t;
typedef __attribute__((ext_vector_type(4))) float f32x4_t;
typedef unsigned short u16;

#define GLOAD_LDS16(g, l)                                 \
  __builtin_amdgcn_global_load_lds(                       \
      (const __attribute__((address_space(1))) void*)(g), \
      (__attribute__((address_space(3))) void*)(l), 16, 0, 0)

__device__ __forceinline__ u16 f2bf(float f) {
  unsigned int u = __float_as_uint(f);
  unsigned int r = (u + 0x7fffu + ((u >> 16) & 1u)) >> 16;
  return (u16)r;
}
__device__ __forceinline__ float bf2f(u16 h) {
  return __uint_as_float(((unsigned int)h) << 16);
}

// sum_a exp(-a*d2), a=0.125*2^k k=0..4, d2 = max(2-2g,0)
__device__ __forceinline__ float mgauss(float g) {
  float h = fmaxf(1.f - g, 0.f);
  float e1 = exp2f(h * EXP_C);
  float e2 = e1 * e1, e4 = e2 * e2, e8 = e4 * e4, e16 = e8 * e8;
  return e1 + e2 + e4 + e8 + e16;
}

__device__ __forceinline__ float wred(float v) {
#pragma unroll
  for (int m = 1; m < 64; m <<= 1) v += __shfl_xor(v, m, 64);
  return v;
}

// fused: zero accumulators + center/l2norm/hi-lo bf16 split for S and Q
__global__ void prep_kernel(const float* __restrict__ S,
                            const float* __restrict__ Q,
                            u16* __restrict__ SHL, u16* __restrict__ QHL,
                            float* __restrict__ accz) {
  int bid = blockIdx.x, tid = threadIdx.x;
  if (bid < 29) {
    int z = bid * 256 + tid;
    if (z < 7280) accz[z] = 0.f;
  }
  int wid = (bid << 2) | (tid >> 6);
  int lane = tid & 63;
  const float* src;
  u16* dst;
  if (wid < 10400) {
    src = S + (size_t)wid * 640;
    dst = SHL + (size_t)wid * 1280;
  } else {
    int w2 = wid - 10400;
    src = Q + (size_t)w2 * 640;
    dst = QHL + (size_t)w2 * 1280;
  }
  float2 v[5];
  float s = 0.f, ss = 0.f;
#pragma unroll
  for (int k = 0; k < 5; ++k) {
    v[k] = ((const float2*)src)[lane + (k << 6)];
    s += v[k].x + v[k].y;
    ss += v[k].x * v[k].x + v[k].y * v[k].y;
  }
#pragma unroll
  for (int m = 1; m < 64; m <<= 1) {
    s += __shfl_xor(s, m, 64);
    ss += __shfl_xor(ss, m, 64);
  }
  float mean = s * (1.f / 640.f);
  float inv = 1.f / sqrtf(fmaxf(ss - s * s * (1.f / 640.f), 0.f) + 1e-12f);
#pragma unroll
  for (int k = 0; k < 5; ++k) {
    int c = (lane + (k << 6)) * 2;
    float t0 = (v[k].x - mean) * inv, t1 = (v[k].y - mean) * inv;
    u16 h0 = f2bf(t0), h1 = f2bf(t1);
    *(ushort2*)(dst + c) = make_ushort2(h0, h1);
    *(ushort2*)(dst + 640 + c) =
        make_ushort2(f2bf(t0 - bf2f(h0)), f2bf(t1 - bf2f(h1)));
  }
}

// one fused kernel: cross (ids 0..1439), selfS band (1440..1695),
// selfQ (1696..1935). m97-style single-buffer 128x128xBK64 core, K=1280.
__global__ __launch_bounds__(256, 4) void grams_kernel(
    const u16* __restrict__ SHL, const u16* __restrict__ QHL,
    float* __restrict__ accS, float* __restrict__ accQ,
    float* __restrict__ accQS) {
  __shared__ __align__(16) u16 sA[128 * 64];
  __shared__ __align__(16) u16 sB[128 * 64];
  const int bid = blockIdx.x;
  const int id = (bid & 7) * 242 + (bid >> 3);  // XCD swizzle (1936 = 8*242)
  const int tid = threadIdx.x;
  const int w = tid >> 6, l = tid & 63;

  int mode, gb, i0, j0, nx, ny;
  const u16 *pX, *pY;
  if (id < 1440) {
    mode = 0;
    gb = id / 90;
    int r = id % 90;
    i0 = (r % 6) * 128;
    j0 = (r / 6) * 128;
    pX = SHL + (size_t)gb * 650 * 1280;
    pY = QHL + (size_t)gb * 1875 * 1280;
    nx = 650;
    ny = 1875;
  } else if (id < 1696) {
    mode = 1;
    int t = id - 1440;
    gb = t >> 4;
    int p = t & 15;
    int ti, tj;
    if (p < 4) {
      ti = p >> 1;
      tj = p & 1;
    } else {
      int q = (p - 4) / 3, r3 = (p - 4) % 3;
      ti = (r3 == 0) ? q + 1 : q + 2;
      tj = (r3 == 1) ? q + 1 : q + 2;
    }
    i0 = ti * 128;
    j0 = tj * 128;
    pX = pY = SHL + (size_t)gb * 650 * 1280;
    nx = ny = 650;
  } else {
    mode = 2;
    gb = id - 1696;
    i0 = 0;
    j0 = 0;
    pX = pY = QHL + (size_t)gb * 125 * 1280;
    nx = ny = 125;
  }

  // staging geometry: thread covers 4 16B-granules of A and of B
  int st_r[4], st_c[4];
#pragma unroll
  for (int i = 0; i < 4; ++i) {
    int s = (w * 4 + i) * 64 + l;
    st_r[i] = s >> 3;
    st_c[i] = ((s & 7) ^ (st_r[i] & 7)) * 8;  // inverse-swizzled source granule
  }

  f32x4_t av[4][4];
#pragma unroll
  for (int i = 0; i < 4; ++i)
#pragma unroll
    for (int j = 0; j < 4; ++j)
#pragma unroll
      for (int r = 0; r < 4; ++r) av[i][j][r] = 0.f;

  const int wr = w >> 1, wc = w & 1;
  const int R0 = wr * 64, C0 = wc * 64;
  const int lr = l & 15, lk8 = (l >> 4) * 8;

  for (int c = 0; c < 20; ++c) {
    int kb = c * 64;
#pragma unroll
    for (int i = 0; i < 4; ++i) {
      int vi = i0 + st_r[i];
      vi = vi < nx ? vi : nx - 1;
      GLOAD_LDS16(pX + (size_t)vi * 1280 + kb + st_c[i], &sA[(w * 4 + i) * 512]);
      int vj = j0 + st_r[i];
      vj = vj < ny ? vj : ny - 1;
      GLOAD_LDS16(pY + (size_t)vj * 1280 + kb + st_c[i], &sB[(w * 4 + i) * 512]);
    }
    __syncthreads();
#pragma unroll
    for (int ks = 0; ks < 2; ++ks) {
      bf16x8_t af[4], bfv[4];
      int kk = ks * 32 + lk8;
#pragma unroll
      for (int t = 0; t < 4; ++t) {
        int rr = R0 + t * 16 + lr;
        af[t] = *(const bf16x8_t*)&sA[rr * 64 + (kk ^ ((rr & 7) << 3))];
        int cc = C0 + t * 16 + lr;
        bfv[t] = *(const bf16x8_t*)&sB[cc * 64 + (kk ^ ((cc & 7) << 3))];
      }
#pragma unroll
      for (int i = 0; i < 4; ++i)
#pragma unroll
        for (int j = 0; j < 4; ++j)
          av[i][j] = __builtin_amdgcn_mfma_f32_16x16x32_bf16(af[i], bfv[j],
                                                             av[i][j], 0, 0, 0);
    }
    __syncthreads();
  }

  // ---- epilogue ----
  int gcv[4];
  bool cvv[4];
#pragma unroll
  for (int j = 0; j < 4; ++j) {
    gcv[j] = j0 + C0 + j * 16 + lr;
    cvv[j] = gcv[j] < ny;
  }

  if (mode == 0) {
    const int cbi = (i0 + R0) / 130;
    const int cbj = (j0 + C0) / 25;
    int cjr[4];
#pragma unroll
    for (int j = 0; j < 4; ++j) cjr[j] = gcv[j] / 25 - cbj;
    float ce[2][4] = {{0.f, 0.f, 0.f, 0.f}, {0.f, 0.f, 0.f, 0.f}};
#pragma unroll
    for (int i = 0; i < 4; ++i)
#pragma unroll
      for (int rr = 0; rr < 4; ++rr) {
        int gr = i0 + R0 + i * 16 + (l >> 4) * 4 + rr;
        bool rv = gr < 650;
        bool ra = (gr / 130) == cbi;
#pragma unroll
        for (int j = 0; j < 4; ++j) {
          float kv = mgauss(av[i][j][rr]);
          kv = (rv && cvv[j]) ? kv : 0.f;
          float k0 = ra ? kv : 0.f;
          ce[0][j] += k0;
          ce[1][j] += kv - k0;
        }
      }
#pragma unroll
    for (int a = 0; a < 2; ++a)
#pragma unroll
      for (int bq = 0; bq < 4; ++bq) {
        float t = 0.f;
#pragma unroll
        for (int j = 0; j < 4; ++j) t += (cjr[j] == bq) ? ce[a][j] : 0.f;
        t = wred(t);
        if (l == 0) {
          int ci = cbi + a, cj = cbj + bq;
          if (ci < 5 && cj < 75) atomicAdd(&accQS[gb * 375 + cj * 5 + ci], t);
        }
      }
  } else if (mode == 1) {
    const int cbi = (i0 + R0) / 130;
    int ccv[4];
#pragma unroll
    for (int j = 0; j < 4; ++j) ccv[j] = gcv[j] / 130;
    float ce[2][4] = {{0.f, 0.f, 0.f, 0.f}, {0.f, 0.f, 0.f, 0.f}};
#pragma unroll
    for (int i = 0; i < 4; ++i)
#pragma unroll
      for (int rr = 0; rr < 4; ++rr) {
        int gr = i0 + R0 + i * 16 + (l >> 4) * 4 + rr;
        bool rv = gr < 650;
        int rc = gr / 130;
        bool ra = rc == cbi;
#pragma unroll
        for (int j = 0; j < 4; ++j) {
          float kv = mgauss(av[i][j][rr]);
          bool val = rv && cvv[j] && (ccv[j] == rc) && (gr != gcv[j]);
          kv = val ? kv : 0.f;
          float k0 = ra ? kv : 0.f;
          ce[0][j] += k0;
          ce[1][j] += kv - k0;
        }
      }
#pragma unroll
    for (int a = 0; a < 2; ++a) {
      float t = wred(ce[a][0] + ce[a][1] + ce[a][2] + ce[a][3]);
      if (l == 0) {
        int ci = cbi + a;
        if (ci < 5) atomicAdd(&accS[gb * 5 + ci], t);
      }
    }
  } else {
    const int cbi = R0 / 25;
    int ccv[4];
#pragma unroll
    for (int j = 0; j < 4; ++j) ccv[j] = gcv[j] / 25;
    float ce[4][4] = {{0.f, 0.f, 0.f, 0.f},
                      {0.f, 0.f, 0.f, 0.f},
                      {0.f, 0.f, 0.f, 0.f},
                      {0.f, 0.f, 0.f, 0.f}};
#pragma unroll
    for (int i = 0; i < 4; ++i)
#pragma unroll
      for (int rr = 0; rr < 4; ++rr) {
        int gr = R0 + i * 16 + (l >> 4) * 4 + rr;
        bool rv = gr < 125;
        int rc = gr / 25;
        int ar = rc - cbi;
#pragma unroll
        for (int j = 0; j < 4; ++j) {
          float kv = mgauss(av[i][j][rr]);
          bool val = rv && cvv[j] && (ccv[j] == rc) && (gr != gcv[j]);
          kv = val ? kv : 0.f;
#pragma unroll
          for (int a = 0; a < 4; ++a) ce[a][j] += (ar == a) ? kv : 0.f;
        }
      }
#pragma unroll
    for (int a = 0; a < 4; ++a) {
      float t = wred(ce[a][0] + ce[a][1] + ce[a][2] + ce[a][3]);
      if (l == 0) {
        int ci = cbi + a;
        if (ci < 5) atomicAdd(&accQ[gb * 5 + ci], t);
      }
    }
  }
}

__global__ void finalize_kernel(const float* __restrict__ accS,
                                const float* __restrict__ accQ,
                                const float* __restrict__ accQS,
                                float* __restrict__ out) {
  int t = blockIdx.x * blockDim.x + threadIdx.x;
  if (t >= 6000) return;
  int w = t % 5;
  int bq = t / 5;
  int b = t / 375;
  out[t] = accS[b * 5 + w] * (1.f / (130.f * 129.f)) +
           accQ[bq] * (1.f / (25.f * 24.f)) - accQS[t] * (2.f / (130.f * 25.f));
}

extern "C" void kernel_launch(void* const* d_in, const int* in_sizes, int n_in,
                              void* d_out, int out_size, void* d_ws,
                              size_t ws_size, hipStream_t stream) {
  const float* S = (const float*)d_in[0];  // [16,5,130,640]
  const float* Q = (const float*)d_in[1];  // [16,75,25,640]
  float* ws = (float*)d_ws;
  float* accS = ws + 0;
  float* accQ = ws + 80;
  float* accQS = ws + 1280;
  u16* SHL = (u16*)(ws + 7280);
  u16* QHL = SHL + (size_t)10400 * 1280;
  float* out = (float*)d_out;

  prep_kernel<<<10100, 256, 0, stream>>>(S, Q, SHL, QHL, ws);
  grams_kernel<<<1936, 256, 0, stream>>>(SHL, QHL, accS, accQ, accQS);
  finalize_kernel<<<24, 256, 0, stream>>>(accS, accQ, accQS, out);
}

// Round 5
// 238.154 us; speedup vs baseline: 6.5943x; 1.1847x over previous
//
#include <hip/hip_runtime.h>
#include <math.h>

// ws layout (floats):
//   accS [80] @0, accQ [1200] @80, accQS [6000] @1280, SHL(u16) @7280,
//   QHL(u16) after SHL. SHL: 10400 rows x 640 u16; QHL: 30000 x 640 u16.

#define EXP_C (-0.25f * 1.44269504088896340736f)  // 2*(-0.125)*log2(e)

typedef __attribute__((ext_vector_type(8))) short bf16x8_t;
typedef __attribute__((ext_vector_type(4))) float f32x4_t;
typedef unsigned short u16;

#define GLOAD_LDS16(g, l)                                 \
  __builtin_amdgcn_global_load_lds(                       \
      (const __attribute__((address_space(1))) void*)(g), \
      (__attribute__((address_space(3))) void*)(l), 16, 0, 0)

__device__ __forceinline__ u16 f2bf(float f) {
  unsigned int u = __float_as_uint(f);
  unsigned int r = (u + 0x7fffu + ((u >> 16) & 1u)) >> 16;
  return (u16)r;
}

// sum_a exp(-a*d2), a=0.125*2^k k=0..4, d2 = max(2-2g,0)
__device__ __forceinline__ float mgauss(float g) {
  float h = fmaxf(1.f - g, 0.f);
  float e1 = exp2f(h * EXP_C);
  float e2 = e1 * e1, e4 = e2 * e2, e8 = e4 * e4, e16 = e8 * e8;
  return e1 + e2 + e4 + e8 + e16;
}

__device__ __forceinline__ float wred(float v) {
#pragma unroll
  for (int m = 1; m < 64; m <<= 1) v += __shfl_xor(v, m, 64);
  return v;
}

// fused: zero accumulators + center/l2norm/bf16 cast for S and Q (hi only;
// lo-plane dropped: its gram contribution ~2^-18, negligible vs observed err)
__global__ void prep_kernel(const float* __restrict__ S,
                            const float* __restrict__ Q,
                            u16* __restrict__ SHL, u16* __restrict__ QHL,
                            float* __restrict__ accz) {
  int bid = blockIdx.x, tid = threadIdx.x;
  if (bid < 29) {
    int z = bid * 256 + tid;
    if (z < 7280) accz[z] = 0.f;
  }
  int wid = (bid << 2) | (tid >> 6);
  int lane = tid & 63;
  const float* src;
  u16* dst;
  if (wid < 10400) {
    src = S + (size_t)wid * 640;
    dst = SHL + (size_t)wid * 640;
  } else {
    int w2 = wid - 10400;
    src = Q + (size_t)w2 * 640;
    dst = QHL + (size_t)w2 * 640;
  }
  const float4* s4 = (const float4*)src;
  float4 a = s4[lane];
  float4 b = s4[lane + 64];
  float4 c = make_float4(0.f, 0.f, 0.f, 0.f);
  if (lane < 32) c = s4[lane + 128];
  float s = a.x + a.y + a.z + a.w + b.x + b.y + b.z + b.w + c.x + c.y + c.z +
            c.w;
  float ss = a.x * a.x + a.y * a.y + a.z * a.z + a.w * a.w + b.x * b.x +
             b.y * b.y + b.z * b.z + b.w * b.w + c.x * c.x + c.y * c.y +
             c.z * c.z + c.w * c.w;
#pragma unroll
  for (int m = 1; m < 64; m <<= 1) {
    s += __shfl_xor(s, m, 64);
    ss += __shfl_xor(ss, m, 64);
  }
  float mean = s * (1.f / 640.f);
  float inv = 1.f / sqrtf(fmaxf(ss - s * s * (1.f / 640.f), 0.f) + 1e-12f);
  ushort4* d4 = (ushort4*)dst;
  d4[lane] = make_ushort4(f2bf((a.x - mean) * inv), f2bf((a.y - mean) * inv),
                          f2bf((a.z - mean) * inv), f2bf((a.w - mean) * inv));
  d4[lane + 64] =
      make_ushort4(f2bf((b.x - mean) * inv), f2bf((b.y - mean) * inv),
                   f2bf((b.z - mean) * inv), f2bf((b.w - mean) * inv));
  if (lane < 32)
    d4[lane + 128] =
        make_ushort4(f2bf((c.x - mean) * inv), f2bf((c.y - mean) * inv),
                     f2bf((c.z - mean) * inv), f2bf((c.w - mean) * inv));
}

// one fused kernel: cross (ids 0..1439), selfS band (1440..1695),
// selfQ (1696..1935). m97-style single-buffer 128x128xBK64 core, K=640.
__global__ __launch_bounds__(256, 4) void grams_kernel(
    const u16* __restrict__ SHL, const u16* __restrict__ QHL,
    float* __restrict__ accS, float* __restrict__ accQ,
    float* __restrict__ accQS) {
  __shared__ __align__(16) u16 sA[128 * 64];
  __shared__ __align__(16) u16 sB[128 * 64];
  const int bid = blockIdx.x;
  const int id = (bid & 7) * 242 + (bid >> 3);  // XCD swizzle (1936 = 8*242)
  const int tid = threadIdx.x;
  const int w = tid >> 6, l = tid & 63;

  int mode, gb, i0, j0, nx, ny;
  const u16 *pX, *pY;
  if (id < 1440) {
    mode = 0;
    gb = id / 90;
    int r = id % 90;
    i0 = (r % 6) * 128;
    j0 = (r / 6) * 128;
    pX = SHL + (size_t)gb * 650 * 640;
    pY = QHL + (size_t)gb * 1875 * 640;
    nx = 650;
    ny = 1875;
  } else if (id < 1696) {
    mode = 1;
    int t = id - 1440;
    gb = t >> 4;
    int p = t & 15;
    int ti, tj;
    if (p < 4) {
      ti = p >> 1;
      tj = p & 1;
    } else {
      int q = (p - 4) / 3, r3 = (p - 4) % 3;
      ti = (r3 == 0) ? q + 1 : q + 2;
      tj = (r3 == 1) ? q + 1 : q + 2;
    }
    i0 = ti * 128;
    j0 = tj * 128;
    pX = pY = SHL + (size_t)gb * 650 * 640;
    nx = ny = 650;
  } else {
    mode = 2;
    gb = id - 1696;
    i0 = 0;
    j0 = 0;
    pX = pY = QHL + (size_t)gb * 125 * 640;
    nx = ny = 125;
  }

  // staging geometry: thread covers 4 16B-granules of A and of B
  int st_r[4], st_c[4];
#pragma unroll
  for (int i = 0; i < 4; ++i) {
    int s = (w * 4 + i) * 64 + l;
    st_r[i] = s >> 3;
    st_c[i] = ((s & 7) ^ (st_r[i] & 7)) * 8;  // inverse-swizzled source granule
  }

  f32x4_t av[4][4];
#pragma unroll
  for (int i = 0; i < 4; ++i)
#pragma unroll
    for (int j = 0; j < 4; ++j)
#pragma unroll
      for (int r = 0; r < 4; ++r) av[i][j][r] = 0.f;

  const int wr = w >> 1, wc = w & 1;
  const int R0 = wr * 64, C0 = wc * 64;
  const int lr = l & 15, lk8 = (l >> 4) * 8;

  for (int c = 0; c < 10; ++c) {
    int kb = c * 64;
#pragma unroll
    for (int i = 0; i < 4; ++i) {
      int vi = i0 + st_r[i];
      vi = vi < nx ? vi : nx - 1;
      GLOAD_LDS16(pX + (size_t)vi * 640 + kb + st_c[i], &sA[(w * 4 + i) * 512]);
      int vj = j0 + st_r[i];
      vj = vj < ny ? vj : ny - 1;
      GLOAD_LDS16(pY + (size_t)vj * 640 + kb + st_c[i], &sB[(w * 4 + i) * 512]);
    }
    __syncthreads();
#pragma unroll
    for (int ks = 0; ks < 2; ++ks) {
      bf16x8_t af[4], bfv[4];
      int kk = ks * 32 + lk8;
#pragma unroll
      for (int t = 0; t < 4; ++t) {
        int rr = R0 + t * 16 + lr;
        af[t] = *(const bf16x8_t*)&sA[rr * 64 + (kk ^ ((rr & 7) << 3))];
        int cc = C0 + t * 16 + lr;
        bfv[t] = *(const bf16x8_t*)&sB[cc * 64 + (kk ^ ((cc & 7) << 3))];
      }
#pragma unroll
      for (int i = 0; i < 4; ++i)
#pragma unroll
        for (int j = 0; j < 4; ++j)
          av[i][j] = __builtin_amdgcn_mfma_f32_16x16x32_bf16(af[i], bfv[j],
                                                             av[i][j], 0, 0, 0);
    }
    __syncthreads();
  }

  // ---- epilogue ----
  int gcv[4];
  bool cvv[4];
#pragma unroll
  for (int j = 0; j < 4; ++j) {
    gcv[j] = j0 + C0 + j * 16 + lr;
    cvv[j] = gcv[j] < ny;
  }

  if (mode == 0) {
    const int cbi = (i0 + R0) / 130;
    const int cbj = (j0 + C0) / 25;
    int cjr[4];
#pragma unroll
    for (int j = 0; j < 4; ++j) cjr[j] = gcv[j] / 25 - cbj;
    float ce[2][4] = {{0.f, 0.f, 0.f, 0.f}, {0.f, 0.f, 0.f, 0.f}};
#pragma unroll
    for (int i = 0; i < 4; ++i)
#pragma unroll
      for (int rr = 0; rr < 4; ++rr) {
        int gr = i0 + R0 + i * 16 + (l >> 4) * 4 + rr;
        bool rv = gr < 650;
        bool ra = (gr / 130) == cbi;
#pragma unroll
        for (int j = 0; j < 4; ++j) {
          float kv = mgauss(av[i][j][rr]);
          kv = (rv && cvv[j]) ? kv : 0.f;
          float k0 = ra ? kv : 0.f;
          ce[0][j] += k0;
          ce[1][j] += kv - k0;
        }
      }
#pragma unroll
    for (int a = 0; a < 2; ++a)
#pragma unroll
      for (int bq = 0; bq < 4; ++bq) {
        float t = 0.f;
#pragma unroll
        for (int j = 0; j < 4; ++j) t += (cjr[j] == bq) ? ce[a][j] : 0.f;
        t = wred(t);
        if (l == 0) {
          int ci = cbi + a, cj = cbj + bq;
          if (ci < 5 && cj < 75) atomicAdd(&accQS[gb * 375 + cj * 5 + ci], t);
        }
      }
  } else if (mode == 1) {
    const int cbi = (i0 + R0) / 130;
    int ccv[4];
#pragma unroll
    for (int j = 0; j < 4; ++j) ccv[j] = gcv[j] / 130;
    float ce[2][4] = {{0.f, 0.f, 0.f, 0.f}, {0.f, 0.f, 0.f, 0.f}};
#pragma unroll
    for (int i = 0; i < 4; ++i)
#pragma unroll
      for (int rr = 0; rr < 4; ++rr) {
        int gr = i0 + R0 + i * 16 + (l >> 4) * 4 + rr;
        bool rv = gr < 650;
        int rc = gr / 130;
        bool ra = rc == cbi;
#pragma unroll
        for (int j = 0; j < 4; ++j) {
          float kv = mgauss(av[i][j][rr]);
          bool val = rv && cvv[j] && (ccv[j] == rc) && (gr != gcv[j]);
          kv = val ? kv : 0.f;
          float k0 = ra ? kv : 0.f;
          ce[0][j] += k0;
          ce[1][j] += kv - k0;
        }
      }
#pragma unroll
    for (int a = 0; a < 2; ++a) {
      float t = wred(ce[a][0] + ce[a][1] + ce[a][2] + ce[a][3]);
      if (l == 0) {
        int ci = cbi + a;
        if (ci < 5) atomicAdd(&accS[gb * 5 + ci], t);
      }
    }
  } else {
    const int cbi = R0 / 25;
    int ccv[4];
#pragma unroll
    for (int j = 0; j < 4; ++j) ccv[j] = gcv[j] / 25;
    float ce[4][4] = {{0.f, 0.f, 0.f, 0.f},
                      {0.f, 0.f, 0.f, 0.f},
                      {0.f, 0.f, 0.f, 0.f},
                      {0.f, 0.f, 0.f, 0.f}};
#pragma unroll
    for (int i = 0; i < 4; ++i)
#pragma unroll
      for (int rr = 0; rr < 4; ++rr) {
        int gr = R0 + i * 16 + (l >> 4) * 4 + rr;
        bool rv = gr < 125;
        int rc = gr / 25;
        int ar = rc - cbi;
#pragma unroll
        for (int j = 0; j < 4; ++j) {
          float kv = mgauss(av[i][j][rr]);
          bool val = rv && cvv[j] && (ccv[j] == rc) && (gr != gcv[j]);
          kv = val ? kv : 0.f;
#pragma unroll
          for (int a = 0; a < 4; ++a) ce[a][j] += (ar == a) ? kv : 0.f;
        }
      }
#pragma unroll
    for (int a = 0; a < 4; ++a) {
      float t = wred(ce[a][0] + ce[a][1] + ce[a][2] + ce[a][3]);
      if (l == 0) {
        int ci = cbi + a;
        if (ci < 5) atomicAdd(&accQ[gb * 5 + ci], t);
      }
    }
  }
}

__global__ void finalize_kernel(const float* __restrict__ accS,
                                const float* __restrict__ accQ,
                                const float* __restrict__ accQS,
                                float* __restrict__ out) {
  int t = blockIdx.x * blockDim.x + threadIdx.x;
  if (t >= 6000) return;
  int w = t % 5;
  int bq = t / 5;
  int b = t / 375;
  out[t] = accS[b * 5 + w] * (1.f / (130.f * 129.f)) +
           accQ[bq] * (1.f / (25.f * 24.f)) - accQS[t] * (2.f / (130.f * 25.f));
}

extern "C" void kernel_launch(void* const* d_in, const int* in_sizes, int n_in,
                              void* d_out, int out_size, void* d_ws,
                              size_t ws_size, hipStream_t stream) {
  const float* S = (const float*)d_in[0];  // [16,5,130,640]
  const float* Q = (const float*)d_in[1];  // [16,75,25,640]
  float* ws = (float*)d_ws;
  float* accS = ws + 0;
  float* accQ = ws + 80;
  float* accQS = ws + 1280;
  u16* SHL = (u16*)(ws + 7280);
  u16* QHL = SHL + (size_t)10400 * 640;
  float* out = (float*)d_out;

  prep_kernel<<<10100, 256, 0, stream>>>(S, Q, SHL, QHL, ws);
  grams_kernel<<<1936, 256, 0, stream>>>(SHL, QHL, accS, accQ, accQS);
  finalize_kernel<<<24, 256, 0, stream>>>(accS, accQ, accQS, out);
}

// Round 6
// 215.970 us; speedup vs baseline: 7.2716x; 1.1027x over previous
//
#include <hip/hip_runtime.h>
#include <math.h>

// ws layout (floats):
//   accS [80] @0, accQ [1200] @80, accQS [6000] @1280, SHL(u16) @7280,
//   QHL(u16) after SHL. SHL: 10400 rows x 640 u16; QHL: 30000 x 640 u16.

#define EXP_C (-0.25f * 1.44269504088896340736f)  // 2*(-0.125)*log2(e)

typedef __attribute__((ext_vector_type(8))) short bf16x8_t;
typedef __attribute__((ext_vector_type(4))) float f32x4_t;
typedef unsigned short u16;

#define GLOAD_LDS16(g, l)                                 \
  __builtin_amdgcn_global_load_lds(                       \
      (const __attribute__((address_space(1))) void*)(g), \
      (__attribute__((address_space(3))) void*)(l), 16, 0, 0)

__device__ __forceinline__ u16 f2bf(float f) {
  unsigned int u = __float_as_uint(f);
  unsigned int r = (u + 0x7fffu + ((u >> 16) & 1u)) >> 16;
  return (u16)r;
}

// sum_a exp(-a*d2), a=0.125*2^k k=0..4, d2 = max(2-2g,0)
__device__ __forceinline__ float mgauss(float g) {
  float h = fmaxf(1.f - g, 0.f);
  float e1 = exp2f(h * EXP_C);
  float e2 = e1 * e1, e4 = e2 * e2, e8 = e4 * e4, e16 = e8 * e8;
  return e1 + e2 + e4 + e8 + e16;
}

__device__ __forceinline__ float wred(float v) {
#pragma unroll
  for (int m = 1; m < 64; m <<= 1) v += __shfl_xor(v, m, 64);
  return v;
}

// fused: zero accumulators + center/l2norm/bf16 cast for S and Q (hi only;
// lo-plane dropped: its gram contribution ~2^-18, negligible vs observed err)
__global__ void prep_kernel(const float* __restrict__ S,
                            const float* __restrict__ Q,
                            u16* __restrict__ SHL, u16* __restrict__ QHL,
                            float* __restrict__ accz) {
  int bid = blockIdx.x, tid = threadIdx.x;
  if (bid < 29) {
    int z = bid * 256 + tid;
    if (z < 7280) accz[z] = 0.f;
  }
  int wid = (bid << 2) | (tid >> 6);
  int lane = tid & 63;
  const float* src;
  u16* dst;
  if (wid < 10400) {
    src = S + (size_t)wid * 640;
    dst = SHL + (size_t)wid * 640;
  } else {
    int w2 = wid - 10400;
    src = Q + (size_t)w2 * 640;
    dst = QHL + (size_t)w2 * 640;
  }
  const float4* s4 = (const float4*)src;
  float4 a = s4[lane];
  float4 b = s4[lane + 64];
  float4 c = make_float4(0.f, 0.f, 0.f, 0.f);
  if (lane < 32) c = s4[lane + 128];
  float s = a.x + a.y + a.z + a.w + b.x + b.y + b.z + b.w + c.x + c.y + c.z +
            c.w;
  float ss = a.x * a.x + a.y * a.y + a.z * a.z + a.w * a.w + b.x * b.x +
             b.y * b.y + b.z * b.z + b.w * b.w + c.x * c.x + c.y * c.y +
             c.z * c.z + c.w * c.w;
#pragma unroll
  for (int m = 1; m < 64; m <<= 1) {
    s += __shfl_xor(s, m, 64);
    ss += __shfl_xor(ss, m, 64);
  }
  float mean = s * (1.f / 640.f);
  float inv = 1.f / sqrtf(fmaxf(ss - s * s * (1.f / 640.f), 0.f) + 1e-12f);
  ushort4* d4 = (ushort4*)dst;
  d4[lane] = make_ushort4(f2bf((a.x - mean) * inv), f2bf((a.y - mean) * inv),
                          f2bf((a.z - mean) * inv), f2bf((a.w - mean) * inv));
  d4[lane + 64] =
      make_ushort4(f2bf((b.x - mean) * inv), f2bf((b.y - mean) * inv),
                   f2bf((b.z - mean) * inv), f2bf((b.w - mean) * inv));
  if (lane < 32)
    d4[lane + 128] =
        make_ushort4(f2bf((c.x - mean) * inv), f2bf((c.y - mean) * inv),
                     f2bf((c.z - mean) * inv), f2bf((c.w - mean) * inv));
}

// one fused kernel: cross (ids 0..1439), selfS band (1440..1695),
// selfQ (1696..1935). 128x128xBK64 core, K=640, 2-phase double-buffered:
// STAGE(next) issued before COMPUTE(cur), one barrier per iteration.
__global__ __launch_bounds__(256, 2) void grams_kernel(
    const u16* __restrict__ SHL, const u16* __restrict__ QHL,
    float* __restrict__ accS, float* __restrict__ accQ,
    float* __restrict__ accQS) {
  __shared__ __align__(16) u16 sA[2][128 * 64];
  __shared__ __align__(16) u16 sB[2][128 * 64];
  const int bid = blockIdx.x;
  const int id = (bid & 7) * 242 + (bid >> 3);  // XCD swizzle (1936 = 8*242)
  const int tid = threadIdx.x;
  const int w = tid >> 6, l = tid & 63;

  int mode, gb, i0, j0, nx, ny;
  const u16 *pX, *pY;
  if (id < 1440) {
    mode = 0;
    gb = id / 90;
    int r = id % 90;
    i0 = (r % 6) * 128;
    j0 = (r / 6) * 128;
    pX = SHL + (size_t)gb * 650 * 640;
    pY = QHL + (size_t)gb * 1875 * 640;
    nx = 650;
    ny = 1875;
  } else if (id < 1696) {
    mode = 1;
    int t = id - 1440;
    gb = t >> 4;
    int p = t & 15;
    int ti, tj;
    if (p < 4) {
      ti = p >> 1;
      tj = p & 1;
    } else {
      int q = (p - 4) / 3, r3 = (p - 4) % 3;
      ti = (r3 == 0) ? q + 1 : q + 2;
      tj = (r3 == 1) ? q + 1 : q + 2;
    }
    i0 = ti * 128;
    j0 = tj * 128;
    pX = pY = SHL + (size_t)gb * 650 * 640;
    nx = ny = 650;
  } else {
    mode = 2;
    gb = id - 1696;
    i0 = 0;
    j0 = 0;
    pX = pY = QHL + (size_t)gb * 125 * 640;
    nx = ny = 125;
  }

  // staging geometry: thread covers 4 16B-granules of A and of B; row
  // pointers precomputed (clamped), source pre-swizzled so LDS dest is linear
  const u16* gA[4];
  const u16* gB[4];
#pragma unroll
  for (int i = 0; i < 4; ++i) {
    int s = (w * 4 + i) * 64 + l;
    int r = s >> 3;
    int c16 = ((s & 7) ^ (r & 7)) * 8;  // inverse-swizzled source granule
    int vi = i0 + r;
    vi = vi < nx ? vi : nx - 1;
    gA[i] = pX + (size_t)vi * 640 + c16;
    int vj = j0 + r;
    vj = vj < ny ? vj : ny - 1;
    gB[i] = pY + (size_t)vj * 640 + c16;
  }

  f32x4_t av[4][4];
#pragma unroll
  for (int i = 0; i < 4; ++i)
#pragma unroll
    for (int j = 0; j < 4; ++j)
#pragma unroll
      for (int r = 0; r < 4; ++r) av[i][j][r] = 0.f;

  const int wr = w >> 1, wc = w & 1;
  const int R0 = wr * 64, C0 = wc * 64;
  const int lr = l & 15, lk8 = (l >> 4) * 8;

#define STAGE(bb, c)                                          \
  {                                                           \
    int kb = (c) * 64;                                        \
    _Pragma("unroll") for (int i = 0; i < 4; ++i) {           \
      GLOAD_LDS16(gA[i] + kb, &sA[bb][(w * 4 + i) * 512]);    \
      GLOAD_LDS16(gB[i] + kb, &sB[bb][(w * 4 + i) * 512]);    \
    }                                                         \
  }

#define COMPUTE(bb)                                                           \
  {                                                                           \
    _Pragma("unroll") for (int ks = 0; ks < 2; ++ks) {                        \
      bf16x8_t af[4], bfv[4];                                                 \
      int kk = ks * 32 + lk8;                                                 \
      _Pragma("unroll") for (int t = 0; t < 4; ++t) {                         \
        int rr = R0 + t * 16 + lr;                                            \
        af[t] = *(const bf16x8_t*)&sA[bb][rr * 64 + (kk ^ ((rr & 7) << 3))];  \
        int cc = C0 + t * 16 + lr;                                            \
        bfv[t] = *(const bf16x8_t*)&sB[bb][cc * 64 + (kk ^ ((cc & 7) << 3))]; \
      }                                                                       \
      _Pragma("unroll") for (int i = 0; i < 4; ++i)                           \
          _Pragma("unroll") for (int j = 0; j < 4; ++j) av[i][j] =            \
          __builtin_amdgcn_mfma_f32_16x16x32_bf16(af[i], bfv[j], av[i][j], 0, \
                                                  0, 0);                      \
    }                                                                         \
  }

  STAGE(0, 0);
  __syncthreads();
  for (int c = 0; c < 10; ++c) {
    if (c < 9) STAGE((c + 1) & 1, c + 1);
    COMPUTE(c & 1);
    __syncthreads();
  }
#undef STAGE
#undef COMPUTE

  // ---- epilogue ----
  int gcv[4];
  bool cvv[4];
#pragma unroll
  for (int j = 0; j < 4; ++j) {
    gcv[j] = j0 + C0 + j * 16 + lr;
    cvv[j] = gcv[j] < ny;
  }

  if (mode == 0) {
    const int cbi = (i0 + R0) / 130;
    const int cbj = (j0 + C0) / 25;
    int cjr[4];
#pragma unroll
    for (int j = 0; j < 4; ++j) cjr[j] = gcv[j] / 25 - cbj;
    float ce[2][4] = {{0.f, 0.f, 0.f, 0.f}, {0.f, 0.f, 0.f, 0.f}};
#pragma unroll
    for (int i = 0; i < 4; ++i)
#pragma unroll
      for (int rr = 0; rr < 4; ++rr) {
        int gr = i0 + R0 + i * 16 + (l >> 4) * 4 + rr;
        bool rv = gr < 650;
        bool ra = (gr / 130) == cbi;
#pragma unroll
        for (int j = 0; j < 4; ++j) {
          float kv = mgauss(av[i][j][rr]);
          kv = (rv && cvv[j]) ? kv : 0.f;
          float k0 = ra ? kv : 0.f;
          ce[0][j] += k0;
          ce[1][j] += kv - k0;
        }
      }
#pragma unroll
    for (int a = 0; a < 2; ++a)
#pragma unroll
      for (int bq = 0; bq < 4; ++bq) {
        float t = 0.f;
#pragma unroll
        for (int j = 0; j < 4; ++j) t += (cjr[j] == bq) ? ce[a][j] : 0.f;
        t = wred(t);
        if (l == 0) {
          int ci = cbi + a, cj = cbj + bq;
          if (ci < 5 && cj < 75) atomicAdd(&accQS[gb * 375 + cj * 5 + ci], t);
        }
      }
  } else if (mode == 1) {
    const int cbi = (i0 + R0) / 130;
    int ccv[4];
#pragma unroll
    for (int j = 0; j < 4; ++j) ccv[j] = gcv[j] / 130;
    float ce[2][4] = {{0.f, 0.f, 0.f, 0.f}, {0.f, 0.f, 0.f, 0.f}};
#pragma unroll
    for (int i = 0; i < 4; ++i)
#pragma unroll
      for (int rr = 0; rr < 4; ++rr) {
        int gr = i0 + R0 + i * 16 + (l >> 4) * 4 + rr;
        bool rv = gr < 650;
        int rc = gr / 130;
        bool ra = rc == cbi;
#pragma unroll
        for (int j = 0; j < 4; ++j) {
          float kv = mgauss(av[i][j][rr]);
          bool val = rv && cvv[j] && (ccv[j] == rc) && (gr != gcv[j]);
          kv = val ? kv : 0.f;
          float k0 = ra ? kv : 0.f;
          ce[0][j] += k0;
          ce[1][j] += kv - k0;
        }
      }
#pragma unroll
    for (int a = 0; a < 2; ++a) {
      float t = wred(ce[a][0] + ce[a][1] + ce[a][2] + ce[a][3]);
      if (l == 0) {
        int ci = cbi + a;
        if (ci < 5) atomicAdd(&accS[gb * 5 + ci], t);
      }
    }
  } else {
    const int cbi = R0 / 25;
    int ccv[4];
#pragma unroll
    for (int j = 0; j < 4; ++j) ccv[j] = gcv[j] / 25;
    float ce[4][4] = {{0.f, 0.f, 0.f, 0.f},
                      {0.f, 0.f, 0.f, 0.f},
                      {0.f, 0.f, 0.f, 0.f},
                      {0.f, 0.f, 0.f, 0.f}};
#pragma unroll
    for (int i = 0; i < 4; ++i)
#pragma unroll
      for (int rr = 0; rr < 4; ++rr) {
        int gr = R0 + i * 16 + (l >> 4) * 4 + rr;
        bool rv = gr < 125;
        int rc = gr / 25;
        int ar = rc - cbi;
#pragma unroll
        for (int j = 0; j < 4; ++j) {
          float kv = mgauss(av[i][j][rr]);
          bool val = rv && cvv[j] && (ccv[j] == rc) && (gr != gcv[j]);
          kv = val ? kv : 0.f;
#pragma unroll
          for (int a = 0; a < 4; ++a) ce[a][j] += (ar == a) ? kv : 0.f;
        }
      }
#pragma unroll
    for (int a = 0; a < 4; ++a) {
      float t = wred(ce[a][0] + ce[a][1] + ce[a][2] + ce[a][3]);
      if (l == 0) {
        int ci = cbi + a;
        if (ci < 5) atomicAdd(&accQ[gb * 5 + ci], t);
      }
    }
  }
}

__global__ void finalize_kernel(const float* __restrict__ accS,
                                const float* __restrict__ accQ,
                                const float* __restrict__ accQS,
                                float* __restrict__ out) {
  int t = blockIdx.x * blockDim.x + threadIdx.x;
  if (t >= 6000) return;
  int w = t % 5;
  int bq = t / 5;
  int b = t / 375;
  out[t] = accS[b * 5 + w] * (1.f / (130.f * 129.f)) +
           accQ[bq] * (1.f / (25.f * 24.f)) - accQS[t] * (2.f / (130.f * 25.f));
}

extern "C" void kernel_launch(void* const* d_in, const int* in_sizes, int n_in,
                              void* d_out, int out_size, void* d_ws,
                              size_t ws_size, hipStream_t stream) {
  const float* S = (const float*)d_in[0];  // [16,5,130,640]
  const float* Q = (const float*)d_in[1];  // [16,75,25,640]
  float* ws = (float*)d_ws;
  float* accS = ws + 0;
  float* accQ = ws + 80;
  float* accQS = ws + 1280;
  u16* SHL = (u16*)(ws + 7280);
  u16* QHL = SHL + (size_t)10400 * 640;
  float* out = (float*)d_out;

  prep_kernel<<<10100, 256, 0, stream>>>(S, Q, SHL, QHL, ws);
  grams_kernel<<<1936, 256, 0, stream>>>(SHL, QHL, accS, accQ, accQS);
  finalize_kernel<<<24, 256, 0, stream>>>(accS, accQ, accQS, out);
}